// Round 8
// baseline (604.322 us; speedup 1.0000x reference)
//
#include <hip/hip_runtime.h>

// LorentzBlock: B=2, L=2048, D=768, H=12, DH=64, DFF=3072
// ALPHA=0.25, BLEND=0.5, EPS=1e-5, SCALE=8
// R8: ROOT CAUSE of R0-R7 failures = output dtype. d_out is FLOAT32 (the
// reference returns f32); rounds 0-7 wrote bf16 u16s. The MFMA pipeline's
// values were correct since R3 (R3 MFMA == R5 naive bit-identical under the
// packed misread). This round: R3 MFMA pipeline + fp32 output stores.
// x1 (attn residual) lives in d_out (fp32) and is fully written before read.

typedef unsigned short u16;
typedef __bf16 bfrag __attribute__((ext_vector_type(8)));
typedef float f32x4 __attribute__((ext_vector_type(4)));

#define MFMA(a, b, c) __builtin_amdgcn_mfma_f32_16x16x32_bf16(a, b, c, 0, 0, 0)
#define NEG_BIG (-30000.0f)

__device__ __forceinline__ float bf2f(u16 u) {
  unsigned int v = ((unsigned int)u) << 16;
  float f; __builtin_memcpy(&f, &v, 4); return f;
}
__device__ __forceinline__ u16 f2bf(float f) {
  unsigned int v; __builtin_memcpy(&v, &f, 4);
  v += 0x7fffu + ((v >> 16) & 1u);   // RNE
  return (u16)(v >> 16);
}
__device__ __forceinline__ bfrag ldfrag(const u16* p) {
  bfrag v; __builtin_memcpy(&v, p, 16); return v;
}

// ---------------------------------------------------------------------------
// Mask canonicalization -> float[768] (R4-proven: int32 here; kept generic).
// ---------------------------------------------------------------------------
__global__ __launch_bounds__(256) void mask_conv_k(const void* __restrict__ mask,
                                                   float* __restrict__ mfl) {
  __shared__ int msh;
  if (threadIdx.x == 0) msh = 0;
  __syncthreads();
  const unsigned int* w = (const unsigned int*)mask;
  if (threadIdx.x < 192) {
    const unsigned int v = w[threadIdx.x];
    if ((v & 0xFFFFu) == 0x3F80u) atomicOr(&msh, 4);
    else if (v == 0x3F800000u) atomicOr(&msh, 2);
    else if (v >= 2u) atomicOr(&msh, 1);
  }
  __syncthreads();
  const int m = msh;
  const int mode = (m & 4) ? 3 : (m & 2) ? 2 : (m & 1) ? 1 : 0;
  for (int i = threadIdx.x; i < 768; i += 256) {
    int b;
    if (mode == 3) b = ((const u16*)mask)[i] != 0;
    else if (mode == 2) b = ((const float*)mask)[i] != 0.0f;
    else if (mode == 1) b = ((const unsigned char*)mask)[i] != 0;
    else b = ((const int*)mask)[i] != 0;
    mfl[i] = (float)b;
  }
}

// ---------------------------------------------------------------------------
// Convert 14 fp32 weight segments into the bf16 arena.
// ---------------------------------------------------------------------------
struct Segs {
  const void* src[14];
  int off[14];
  int n[14];
};

__global__ __launch_bounds__(256) void convert_k(Segs segs, u16* __restrict__ dstb) {
  const int seg = blockIdx.y;
  const int n = segs.n[seg];
  u16* dst = dstb + segs.off[seg];
  const float* src = (const float*)segs.src[seg];
  for (int i = (blockIdx.x * 256 + threadIdx.x) * 4; i < n; i += gridDim.x * 1024) {
    float4 v;
    __builtin_memcpy(&v, src + i, 16);
    dst[i] = f2bf(v.x); dst[i + 1] = f2bf(v.y);
    dst[i + 2] = f2bf(v.z); dst[i + 3] = f2bf(v.w);
  }
}

// ---------------------------------------------------------------------------
// Minkowski LayerNorm. fp32 input, bf16 outputs (Y, and optionally Y*m,
// Y*(1-m)). One block per row.
// ---------------------------------------------------------------------------
__global__ __launch_bounds__(256) void mink_norm_k(
    const float* __restrict__ X, const float* __restrict__ mf,
    const u16* __restrict__ w, const u16* __restrict__ bias,
    u16* __restrict__ Y, u16* __restrict__ Ym, u16* __restrict__ Ys) {
  __shared__ float red[8];
  const int row = blockIdx.x, tid = threadIdx.x;
  const int wid = tid >> 6, lane = tid & 63;
  const size_t roff = (size_t)row * 768;

  float xv[3], mv[3];
  int idx[3];
#pragma unroll
  for (int i = 0; i < 3; i++) {
    idx[i] = tid + i * 256;
    xv[i] = X[roff + idx[i]];
    mv[i] = mf[idx[i]];
  }
  float s = xv[0] + xv[1] + xv[2];
#pragma unroll
  for (int o = 32; o >= 1; o >>= 1) s += __shfl_xor(s, o, 64);
  if (lane == 0) red[wid] = s;
  __syncthreads();
  const float mean = (red[0] + red[1] + red[2] + red[3]) * (1.0f / 768.0f);
  __syncthreads();

  float xc[3], ss = 0.0f, sm = 0.0f;
#pragma unroll
  for (int i = 0; i < 3; i++) {
    xc[i] = xv[i] - mean;
    ss += xc[i] * xc[i];
    sm += xc[i] * xc[i] * mv[i];
  }
#pragma unroll
  for (int o = 32; o >= 1; o >>= 1) {
    ss += __shfl_xor(ss, o, 64);
    sm += __shfl_xor(sm, o, 64);
  }
  if (lane == 0) { red[wid] = ss; red[4 + wid] = sm; }
  __syncthreads();
  const float sumsq = red[0] + red[1] + red[2] + red[3];
  const float summ = red[4] + red[5] + red[6] + red[7];
  const float var = sumsq * (1.0f / 768.0f);
  const float eta = sumsq - 2.0f * summ;
  const float rs = 1.0f / sqrtf(var + 1e-5f);
  const float re = 1.0f / sqrtf(fabsf(eta) + 1e-5f);

#pragma unroll
  for (int i = 0; i < 3; i++) {
    const float xn = xc[i] * 0.5f * (rs + re);
    const float y = bf2f(w[idx[i]]) * xn + bf2f(bias[idx[i]]);
    const size_t o = roff + idx[i];
    Y[o] = f2bf(y);
    if (Ym) {
      Ym[o] = f2bf(y * mv[i]);
      Ys[o] = f2bf(y * (1.0f - mv[i]));
    }
  }
}

// ---------------------------------------------------------------------------
// Q Lorentz correction, in place (bf16), folds 1/SCALE.
// ---------------------------------------------------------------------------
__global__ __launch_bounds__(64) void qcorr_k(u16* __restrict__ Q,
                                              const float* __restrict__ mf) {
  const int row = blockIdx.x;
  const int t = threadIdx.x;
  const int h = row % 12;
  const int bl = row / 12;
  const size_t off = (size_t)bl * 768 + h * 64 + t;
  const float q = bf2f(Q[off]);
  const float m = mf[h * 64 + t];
  float q2 = q * q, qm2 = q * q * m;
#pragma unroll
  for (int o = 32; o >= 1; o >>= 1) {
    q2 += __shfl_xor(q2, o, 64);
    qm2 += __shfl_xor(qm2, o, 64);
  }
  const float qn = sqrtf(q2), qtn = sqrtf(qm2);
  const float sf = (qtn > 1e-6f) ? qn / fmaxf(qtn, 1e-8f) : 0.0f;
  Q[off] = f2bf(q * (1.0f - 0.5f * sf * m) * 0.125f);
}

// ---------------------------------------------------------------------------
// C = epi(X @ W^T [+R]) MFMA GEMM, 64x64 tile. bf16 X/W, fp32 accum.
// EPI: 0=none (C bf16), 1=+R residual, R fp32, C fp32, 2=gelu (C bf16),
// 3=silu (C bf16).
// ---------------------------------------------------------------------------
template <int EPI>
__global__ __launch_bounds__(256) void gemm_xwt(
    const u16* __restrict__ X, const u16* __restrict__ W,
    void* __restrict__ Cv, const float* __restrict__ R,
    int M, int N, int K) {
  __shared__ __align__(16) u16 As[64][40];
  __shared__ __align__(16) u16 Bs[64][40];
  const int tid = threadIdx.x;
  const int rowb = blockIdx.y * 64, colb = blockIdx.x * 64;
  const int wid = tid >> 6, lane = tid & 63, lr = lane & 15, lq = lane >> 4;
  const int wrow = (wid >> 1) * 32, wcol = (wid & 1) * 32;
  f32x4 acc[2][2] = {};
  const int lrow = tid >> 2, lcg = (tid & 3) * 8;
  const u16* Xp = X + (size_t)(rowb + lrow) * K + lcg;
  const u16* Wp = W + (size_t)(colb + lrow) * K + lcg;

  for (int k0 = 0; k0 < K; k0 += 32) {
    uint4 av, bv;
    __builtin_memcpy(&av, Xp + k0, 16);
    __builtin_memcpy(&bv, Wp + k0, 16);
    __syncthreads();
    __builtin_memcpy(&As[lrow][lcg], &av, 16);
    __builtin_memcpy(&Bs[lrow][lcg], &bv, 16);
    __syncthreads();
    bfrag a0 = ldfrag(&As[wrow + lr][lq * 8]);
    bfrag a1 = ldfrag(&As[wrow + 16 + lr][lq * 8]);
    bfrag b0 = ldfrag(&Bs[wcol + lr][lq * 8]);
    bfrag b1 = ldfrag(&Bs[wcol + 16 + lr][lq * 8]);
    acc[0][0] = MFMA(a0, b0, acc[0][0]);
    acc[0][1] = MFMA(a0, b1, acc[0][1]);
    acc[1][0] = MFMA(a1, b0, acc[1][0]);
    acc[1][1] = MFMA(a1, b1, acc[1][1]);
  }

#pragma unroll
  for (int i = 0; i < 2; i++)
#pragma unroll
    for (int j = 0; j < 2; j++)
#pragma unroll
      for (int r = 0; r < 4; r++) {
        const int row = rowb + wrow + i * 16 + lq * 4 + r;
        const int col = colb + wcol + j * 16 + lr;
        float v = acc[i][j][r];
        const size_t o = (size_t)row * N + col;
        if (EPI == 1) {
          ((float*)Cv)[o] = v + R[o];
        } else {
          if (EPI == 2) v = 0.5f * v * (1.0f + erff(v * 0.70710678118654752f));
          if (EPI == 3) v = v / (1.0f + __expf(-v));
          ((u16*)Cv)[o] = f2bf(v);
        }
      }
}

// ---------------------------------------------------------------------------
// FFN second layer: Out = X1 + 0.5*(h1@w2^T + ht@w2_t^T + hs@w2_s^T)
// X1/Out fp32, may alias (same-element read-before-write per thread).
// ---------------------------------------------------------------------------
__global__ __launch_bounds__(256) void ffn2_gemm(
    const u16* __restrict__ H1, const u16* __restrict__ Ht,
    const u16* __restrict__ Hs, const u16* __restrict__ W2,
    const u16* __restrict__ W2t, const u16* __restrict__ W2s,
    const float* X1, float* Out) {
  const int N = 768;
  __shared__ __align__(16) u16 As[64][40];
  __shared__ __align__(16) u16 Bs[64][40];
  const int tid = threadIdx.x;
  const int rowb = blockIdx.y * 64, colb = blockIdx.x * 64;
  const int wid = tid >> 6, lane = tid & 63, lr = lane & 15, lq = lane >> 4;
  const int wrow = (wid >> 1) * 32, wcol = (wid & 1) * 32;
  f32x4 acc[2][2] = {};
  const int lrow = tid >> 2, lcg = (tid & 3) * 8;
  const u16* Xs[3] = {H1, Ht, Hs};
  const u16* Ws[3] = {W2, W2t, W2s};
  const int Kseg[3] = {3072, 1536, 1536};

  for (int sg = 0; sg < 3; sg++) {
    const int K = Kseg[sg];
    const u16* Xp = Xs[sg] + (size_t)(rowb + lrow) * K + lcg;
    const u16* Wp = Ws[sg] + (size_t)(colb + lrow) * K + lcg;
    for (int k0 = 0; k0 < K; k0 += 32) {
      uint4 av, bv;
      __builtin_memcpy(&av, Xp + k0, 16);
      __builtin_memcpy(&bv, Wp + k0, 16);
      __syncthreads();
      __builtin_memcpy(&As[lrow][lcg], &av, 16);
      __builtin_memcpy(&Bs[lrow][lcg], &bv, 16);
      __syncthreads();
      bfrag a0 = ldfrag(&As[wrow + lr][lq * 8]);
      bfrag a1 = ldfrag(&As[wrow + 16 + lr][lq * 8]);
      bfrag b0 = ldfrag(&Bs[wcol + lr][lq * 8]);
      bfrag b1 = ldfrag(&Bs[wcol + 16 + lr][lq * 8]);
      acc[0][0] = MFMA(a0, b0, acc[0][0]);
      acc[0][1] = MFMA(a0, b1, acc[0][1]);
      acc[1][0] = MFMA(a1, b0, acc[1][0]);
      acc[1][1] = MFMA(a1, b1, acc[1][1]);
    }
  }

#pragma unroll
  for (int i = 0; i < 2; i++)
#pragma unroll
    for (int j = 0; j < 2; j++)
#pragma unroll
      for (int r = 0; r < 4; r++) {
        const int row = rowb + wrow + i * 16 + lq * 4 + r;
        const int col = colb + wcol + j * 16 + lr;
        const size_t o = (size_t)row * N + col;
        Out[o] = X1[o] + 0.5f * acc[i][j][r];
      }
}

// ---------------------------------------------------------------------------
// Flash attention, causal. Grid (L/64, B*H); 4 waves, 16 q-rows/wave.
// ---------------------------------------------------------------------------
__global__ __launch_bounds__(256) void flash_attn_k(
    const u16* __restrict__ Qc, const u16* __restrict__ Kb,
    const u16* __restrict__ Vb, u16* __restrict__ O) {
  __shared__ __align__(16) u16 Ks[32][72];
  __shared__ __align__(16) u16 Vt[64][40];
  __shared__ __align__(16) u16 Ps[4][16][40];
  const int tid = threadIdx.x, wid = tid >> 6, lane = tid & 63;
  const int lr = lane & 15, lq = lane >> 4;
  const int qb = blockIdx.x * 64;
  const int bh = blockIdx.y;
  const int b = bh / 12, h = bh % 12;
  const int q0 = qb + wid * 16;
  const size_t base = (size_t)b * 2048 * 768 + h * 64;

  bfrag aq[2];
  aq[0] = ldfrag(Qc + base + (size_t)(q0 + lr) * 768 + lq * 8);
  aq[1] = ldfrag(Qc + base + (size_t)(q0 + lr) * 768 + 32 + lq * 8);

  f32x4 o[4] = {};
  float mrow[4] = {NEG_BIG, NEG_BIG, NEG_BIG, NEG_BIG};
  float lrow[4] = {0.0f, 0.0f, 0.0f, 0.0f};

  const int strow = tid >> 3, stc = (tid & 7) * 8;
  const int nt = (qb + 64) / 32;

  for (int kt = 0; kt < nt; kt++) {
    const int kbk = kt * 32;
    uint4 kv, vv;
    __builtin_memcpy(&kv, Kb + base + (size_t)(kbk + strow) * 768 + stc, 16);
    __builtin_memcpy(&vv, Vb + base + (size_t)(kbk + strow) * 768 + stc, 16);
    __syncthreads();
    __builtin_memcpy(&Ks[strow][stc], &kv, 16);
    union { uint4 u; u16 s[8]; } vu; vu.u = vv;
#pragma unroll
    for (int j = 0; j < 8; j++) Vt[stc + j][strow] = vu.s[j];
    __syncthreads();

    if (kbk <= q0 + 15) {
      f32x4 sa = {}, sb = {};
#pragma unroll
      for (int i = 0; i < 2; i++) {
        bfrag bk0 = ldfrag(&Ks[lr][i * 32 + lq * 8]);
        bfrag bk1 = ldfrag(&Ks[16 + lr][i * 32 + lq * 8]);
        sa = MFMA(aq[i], bk0, sa);
        sb = MFMA(aq[i], bk1, sb);
      }
#pragma unroll
      for (int r = 0; r < 4; r++) {
        const int q = q0 + lq * 4 + r;
        float va = (kbk + lr > q) ? NEG_BIG : sa[r];
        float vb2 = (kbk + 16 + lr > q) ? NEG_BIG : sb[r];
        float mx = fmaxf(va, vb2);
#pragma unroll
        for (int off = 8; off >= 1; off >>= 1)
          mx = fmaxf(mx, __shfl_xor(mx, off, 16));
        const float mn = fmaxf(mrow[r], mx);
        const float alpha = __expf(mrow[r] - mn);
        const float pa = __expf(va - mn);
        const float pb = __expf(vb2 - mn);
        float sm2 = pa + pb;
#pragma unroll
        for (int off = 8; off >= 1; off >>= 1) sm2 += __shfl_xor(sm2, off, 16);
        lrow[r] = lrow[r] * alpha + sm2;
        mrow[r] = mn;
#pragma unroll
        for (int dt = 0; dt < 4; dt++) o[dt][r] *= alpha;
        Ps[wid][lq * 4 + r][lr] = f2bf(pa);
        Ps[wid][lq * 4 + r][16 + lr] = f2bf(pb);
      }
      __threadfence_block();
      bfrag pf = ldfrag(&Ps[wid][lr][lq * 8]);
#pragma unroll
      for (int dt = 0; dt < 4; dt++) {
        bfrag bv2 = ldfrag(&Vt[dt * 16 + lr][lq * 8]);
        o[dt] = MFMA(pf, bv2, o[dt]);
      }
    }
  }

#pragma unroll
  for (int r = 0; r < 4; r++) {
    const float inv = 1.0f / fmaxf(lrow[r], 1e-30f);
    const int q = q0 + lq * 4 + r;
#pragma unroll
    for (int dt = 0; dt < 4; dt++)
      O[base + (size_t)q * 768 + dt * 16 + lr] = f2bf(o[dt][r] * inv);
  }
}

// ---------------------------------------------------------------------------
extern "C" void kernel_launch(void* const* d_in, const int* in_sizes, int n_in,
                              void* d_out, int out_size, void* d_ws,
                              size_t ws_size, hipStream_t stream) {
  (void)in_sizes; (void)n_in; (void)out_size; (void)ws_size;
  const float* x = (const float*)d_in[0];
  const void* mask = d_in[2];

  char* ws = (char*)d_ws;
  u16* Wb  = (u16*)(ws);                        // bf16 arena, 23599104 B
  u16* n1h = (u16*)(ws + 23599104);             // 4096x3072 bf16 (later h1)
  u16* Qb  = (u16*)(ws + 48764928);             // 4096x768 (later n2)
  u16* Kb2 = (u16*)(ws + 55056384);             // 4096x768 (later n2m)
  u16* Vb2 = (u16*)(ws + 61347840);             // 4096x768 (later n2s)
  u16* att = (u16*)(ws + 67639296);             // 4096x768 att, later 4096x1536 ht
  u16* hs  = (u16*)(ws + 80222208);             // 4096x1536
  float* mfl = (float*)(ws + 92805120);         // 768 floats (end 92808192)
  float* x1 = (float*)d_out;                    // x1 fp32 lives in d_out

  u16* Wq = Wb + 0,        *Wk = Wb + 589824,   *Wv = Wb + 1179648;
  u16* Wo = Wb + 1769472,  *w1 = Wb + 2359296,  *w1t = Wb + 4718592;
  u16* w1s = Wb + 5898240, *w2 = Wb + 7077888,  *w2t = Wb + 9437184;
  u16* w2s = Wb + 10616832;
  u16* n1w = Wb + 11796480, *n1b = Wb + 11797248;
  u16* n2w = Wb + 11798016, *n2b = Wb + 11798784;

  Segs sg;
  const int srcidx[14] = {3, 4, 5, 6, 7, 9, 11, 8, 10, 12, 13, 14, 15, 16};
  const int offs[14] = {0, 589824, 1179648, 1769472, 2359296, 4718592,
                        5898240, 7077888, 9437184, 10616832,
                        11796480, 11797248, 11798016, 11798784};
  const int ns[14] = {589824, 589824, 589824, 589824, 2359296, 1179648,
                      1179648, 2359296, 1179648, 1179648, 768, 768, 768, 768};
  for (int i = 0; i < 14; i++) {
    sg.src[i] = d_in[srcidx[i]];
    sg.off[i] = offs[i];
    sg.n[i] = ns[i];
  }

  mask_conv_k<<<1, 256, 0, stream>>>(mask, mfl);
  convert_k<<<dim3(2304, 14), 256, 0, stream>>>(sg, Wb);

  mink_norm_k<<<4096, 256, 0, stream>>>(x, mfl, n1w, n1b, n1h, nullptr, nullptr);
  gemm_xwt<0><<<dim3(12, 64), 256, 0, stream>>>(n1h, Wq, Qb, nullptr, 4096, 768, 768);
  gemm_xwt<0><<<dim3(12, 64), 256, 0, stream>>>(n1h, Wk, Kb2, nullptr, 4096, 768, 768);
  gemm_xwt<0><<<dim3(12, 64), 256, 0, stream>>>(n1h, Wv, Vb2, nullptr, 4096, 768, 768);
  qcorr_k<<<49152, 64, 0, stream>>>(Qb, mfl);
  flash_attn_k<<<dim3(32, 24), 256, 0, stream>>>(Qb, Kb2, Vb2, att);
  // x1 = x + att @ Wo^T  (fp32, into d_out)
  gemm_xwt<1><<<dim3(12, 64), 256, 0, stream>>>(att, Wo, x1, x, 4096, 768, 768);
  // n2 (+ masked variants) from x1 — overwrites Q/K/V buffers
  mink_norm_k<<<4096, 256, 0, stream>>>(x1, mfl, n2w, n2b, Qb, Kb2, Vb2);
  gemm_xwt<2><<<dim3(48, 64), 256, 0, stream>>>(Qb, w1, n1h, nullptr, 4096, 3072, 768);
  gemm_xwt<3><<<dim3(24, 64), 256, 0, stream>>>(Kb2, w1t, att, nullptr, 4096, 1536, 768);
  gemm_xwt<2><<<dim3(24, 64), 256, 0, stream>>>(Vb2, w1s, hs, nullptr, 4096, 1536, 768);
  // out = x1 + 0.5*(h1@w2^T + ht@w2_t^T + hs@w2_s^T)  (fp32 d_out, aliased)
  ffn2_gemm<<<dim3(12, 64), 256, 0, stream>>>(n1h, att, hs, w2, w2t, w2s,
                                              x1, (float*)d_out);
}

// Round 9
// 537.654 us; speedup vs baseline: 1.1240x; 1.1240x over previous
//
#include <hip/hip_runtime.h>

// LorentzBlock: B=2, L=2048, D=768, H=12, DH=64, DFF=3072
// R9: flash_attn rewrite (R8 profile: 175us, MfmaUtil 2.9%, 1.5e7 LDS bank
// conflicts). 64-key tiles (half the barriers), register ping-pong prefetch,
// conflict-fixed V transpose (<=4-way writes, 2-way/free fragment reads),
// heavy causal blocks dispatched first. All other kernels unchanged from the
// passing R8 version.

typedef unsigned short u16;
typedef __bf16 bfrag __attribute__((ext_vector_type(8)));
typedef float f32x4 __attribute__((ext_vector_type(4)));

#define MFMA(a, b, c) __builtin_amdgcn_mfma_f32_16x16x32_bf16(a, b, c, 0, 0, 0)
#define NEG_BIG (-30000.0f)

__device__ __forceinline__ float bf2f(u16 u) {
  unsigned int v = ((unsigned int)u) << 16;
  float f; __builtin_memcpy(&f, &v, 4); return f;
}
__device__ __forceinline__ u16 f2bf(float f) {
  unsigned int v; __builtin_memcpy(&v, &f, 4);
  v += 0x7fffu + ((v >> 16) & 1u);   // RNE
  return (u16)(v >> 16);
}
__device__ __forceinline__ bfrag ldfrag(const u16* p) {
  bfrag v; __builtin_memcpy(&v, p, 16); return v;
}

// ---------------------------------------------------------------------------
// Mask canonicalization -> float[768].
// ---------------------------------------------------------------------------
__global__ __launch_bounds__(256) void mask_conv_k(const void* __restrict__ mask,
                                                   float* __restrict__ mfl) {
  __shared__ int msh;
  if (threadIdx.x == 0) msh = 0;
  __syncthreads();
  const unsigned int* w = (const unsigned int*)mask;
  if (threadIdx.x < 192) {
    const unsigned int v = w[threadIdx.x];
    if ((v & 0xFFFFu) == 0x3F80u) atomicOr(&msh, 4);
    else if (v == 0x3F800000u) atomicOr(&msh, 2);
    else if (v >= 2u) atomicOr(&msh, 1);
  }
  __syncthreads();
  const int m = msh;
  const int mode = (m & 4) ? 3 : (m & 2) ? 2 : (m & 1) ? 1 : 0;
  for (int i = threadIdx.x; i < 768; i += 256) {
    int b;
    if (mode == 3) b = ((const u16*)mask)[i] != 0;
    else if (mode == 2) b = ((const float*)mask)[i] != 0.0f;
    else if (mode == 1) b = ((const unsigned char*)mask)[i] != 0;
    else b = ((const int*)mask)[i] != 0;
    mfl[i] = (float)b;
  }
}

// ---------------------------------------------------------------------------
// Convert 14 fp32 weight segments into the bf16 arena.
// ---------------------------------------------------------------------------
struct Segs {
  const void* src[14];
  int off[14];
  int n[14];
};

__global__ __launch_bounds__(256) void convert_k(Segs segs, u16* __restrict__ dstb) {
  const int seg = blockIdx.y;
  const int n = segs.n[seg];
  u16* dst = dstb + segs.off[seg];
  const float* src = (const float*)segs.src[seg];
  for (int i = (blockIdx.x * 256 + threadIdx.x) * 4; i < n; i += gridDim.x * 1024) {
    float4 v;
    __builtin_memcpy(&v, src + i, 16);
    dst[i] = f2bf(v.x); dst[i + 1] = f2bf(v.y);
    dst[i + 2] = f2bf(v.z); dst[i + 3] = f2bf(v.w);
  }
}

// ---------------------------------------------------------------------------
// Minkowski LayerNorm. fp32 input, bf16 outputs.
// ---------------------------------------------------------------------------
__global__ __launch_bounds__(256) void mink_norm_k(
    const float* __restrict__ X, const float* __restrict__ mf,
    const u16* __restrict__ w, const u16* __restrict__ bias,
    u16* __restrict__ Y, u16* __restrict__ Ym, u16* __restrict__ Ys) {
  __shared__ float red[8];
  const int row = blockIdx.x, tid = threadIdx.x;
  const int wid = tid >> 6, lane = tid & 63;
  const size_t roff = (size_t)row * 768;

  float xv[3], mv[3];
  int idx[3];
#pragma unroll
  for (int i = 0; i < 3; i++) {
    idx[i] = tid + i * 256;
    xv[i] = X[roff + idx[i]];
    mv[i] = mf[idx[i]];
  }
  float s = xv[0] + xv[1] + xv[2];
#pragma unroll
  for (int o = 32; o >= 1; o >>= 1) s += __shfl_xor(s, o, 64);
  if (lane == 0) red[wid] = s;
  __syncthreads();
  const float mean = (red[0] + red[1] + red[2] + red[3]) * (1.0f / 768.0f);
  __syncthreads();

  float xc[3], ss = 0.0f, sm = 0.0f;
#pragma unroll
  for (int i = 0; i < 3; i++) {
    xc[i] = xv[i] - mean;
    ss += xc[i] * xc[i];
    sm += xc[i] * xc[i] * mv[i];
  }
#pragma unroll
  for (int o = 32; o >= 1; o >>= 1) {
    ss += __shfl_xor(ss, o, 64);
    sm += __shfl_xor(sm, o, 64);
  }
  if (lane == 0) { red[wid] = ss; red[4 + wid] = sm; }
  __syncthreads();
  const float sumsq = red[0] + red[1] + red[2] + red[3];
  const float summ = red[4] + red[5] + red[6] + red[7];
  const float var = sumsq * (1.0f / 768.0f);
  const float eta = sumsq - 2.0f * summ;
  const float rs = 1.0f / sqrtf(var + 1e-5f);
  const float re = 1.0f / sqrtf(fabsf(eta) + 1e-5f);

#pragma unroll
  for (int i = 0; i < 3; i++) {
    const float xn = xc[i] * 0.5f * (rs + re);
    const float y = bf2f(w[idx[i]]) * xn + bf2f(bias[idx[i]]);
    const size_t o = roff + idx[i];
    Y[o] = f2bf(y);
    if (Ym) {
      Ym[o] = f2bf(y * mv[i]);
      Ys[o] = f2bf(y * (1.0f - mv[i]));
    }
  }
}

// ---------------------------------------------------------------------------
// Q Lorentz correction, in place (bf16), folds 1/SCALE.
// ---------------------------------------------------------------------------
__global__ __launch_bounds__(64) void qcorr_k(u16* __restrict__ Q,
                                              const float* __restrict__ mf) {
  const int row = blockIdx.x;
  const int t = threadIdx.x;
  const int h = row % 12;
  const int bl = row / 12;
  const size_t off = (size_t)bl * 768 + h * 64 + t;
  const float q = bf2f(Q[off]);
  const float m = mf[h * 64 + t];
  float q2 = q * q, qm2 = q * q * m;
#pragma unroll
  for (int o = 32; o >= 1; o >>= 1) {
    q2 += __shfl_xor(q2, o, 64);
    qm2 += __shfl_xor(qm2, o, 64);
  }
  const float qn = sqrtf(q2), qtn = sqrtf(qm2);
  const float sf = (qtn > 1e-6f) ? qn / fmaxf(qtn, 1e-8f) : 0.0f;
  Q[off] = f2bf(q * (1.0f - 0.5f * sf * m) * 0.125f);
}

// ---------------------------------------------------------------------------
// C = epi(X @ W^T [+R]) MFMA GEMM, 64x64 tile (unchanged, R8-proven).
// EPI: 0=none (C bf16), 1=+R fp32 residual (C fp32), 2=gelu, 3=silu.
// ---------------------------------------------------------------------------
template <int EPI>
__global__ __launch_bounds__(256) void gemm_xwt(
    const u16* __restrict__ X, const u16* __restrict__ W,
    void* __restrict__ Cv, const float* __restrict__ R,
    int M, int N, int K) {
  __shared__ __align__(16) u16 As[64][40];
  __shared__ __align__(16) u16 Bs[64][40];
  const int tid = threadIdx.x;
  const int rowb = blockIdx.y * 64, colb = blockIdx.x * 64;
  const int wid = tid >> 6, lane = tid & 63, lr = lane & 15, lq = lane >> 4;
  const int wrow = (wid >> 1) * 32, wcol = (wid & 1) * 32;
  f32x4 acc[2][2] = {};
  const int lrow = tid >> 2, lcg = (tid & 3) * 8;
  const u16* Xp = X + (size_t)(rowb + lrow) * K + lcg;
  const u16* Wp = W + (size_t)(colb + lrow) * K + lcg;

  for (int k0 = 0; k0 < K; k0 += 32) {
    uint4 av, bv;
    __builtin_memcpy(&av, Xp + k0, 16);
    __builtin_memcpy(&bv, Wp + k0, 16);
    __syncthreads();
    __builtin_memcpy(&As[lrow][lcg], &av, 16);
    __builtin_memcpy(&Bs[lrow][lcg], &bv, 16);
    __syncthreads();
    bfrag a0 = ldfrag(&As[wrow + lr][lq * 8]);
    bfrag a1 = ldfrag(&As[wrow + 16 + lr][lq * 8]);
    bfrag b0 = ldfrag(&Bs[wcol + lr][lq * 8]);
    bfrag b1 = ldfrag(&Bs[wcol + 16 + lr][lq * 8]);
    acc[0][0] = MFMA(a0, b0, acc[0][0]);
    acc[0][1] = MFMA(a0, b1, acc[0][1]);
    acc[1][0] = MFMA(a1, b0, acc[1][0]);
    acc[1][1] = MFMA(a1, b1, acc[1][1]);
  }

#pragma unroll
  for (int i = 0; i < 2; i++)
#pragma unroll
    for (int j = 0; j < 2; j++)
#pragma unroll
      for (int r = 0; r < 4; r++) {
        const int row = rowb + wrow + i * 16 + lq * 4 + r;
        const int col = colb + wcol + j * 16 + lr;
        float v = acc[i][j][r];
        const size_t o = (size_t)row * N + col;
        if (EPI == 1) {
          ((float*)Cv)[o] = v + R[o];
        } else {
          if (EPI == 2) v = 0.5f * v * (1.0f + erff(v * 0.70710678118654752f));
          if (EPI == 3) v = v / (1.0f + __expf(-v));
          ((u16*)Cv)[o] = f2bf(v);
        }
      }
}

// ---------------------------------------------------------------------------
// FFN second layer (unchanged): Out = X1 + 0.5*(h1@w2^T + ht@w2_t^T + hs@w2_s^T)
// ---------------------------------------------------------------------------
__global__ __launch_bounds__(256) void ffn2_gemm(
    const u16* __restrict__ H1, const u16* __restrict__ Ht,
    const u16* __restrict__ Hs, const u16* __restrict__ W2,
    const u16* __restrict__ W2t, const u16* __restrict__ W2s,
    const float* X1, float* Out) {
  const int N = 768;
  __shared__ __align__(16) u16 As[64][40];
  __shared__ __align__(16) u16 Bs[64][40];
  const int tid = threadIdx.x;
  const int rowb = blockIdx.y * 64, colb = blockIdx.x * 64;
  const int wid = tid >> 6, lane = tid & 63, lr = lane & 15, lq = lane >> 4;
  const int wrow = (wid >> 1) * 32, wcol = (wid & 1) * 32;
  f32x4 acc[2][2] = {};
  const int lrow = tid >> 2, lcg = (tid & 3) * 8;
  const u16* Xs[3] = {H1, Ht, Hs};
  const u16* Ws[3] = {W2, W2t, W2s};
  const int Kseg[3] = {3072, 1536, 1536};

  for (int sg = 0; sg < 3; sg++) {
    const int K = Kseg[sg];
    const u16* Xp = Xs[sg] + (size_t)(rowb + lrow) * K + lcg;
    const u16* Wp = Ws[sg] + (size_t)(colb + lrow) * K + lcg;
    for (int k0 = 0; k0 < K; k0 += 32) {
      uint4 av, bv;
      __builtin_memcpy(&av, Xp + k0, 16);
      __builtin_memcpy(&bv, Wp + k0, 16);
      __syncthreads();
      __builtin_memcpy(&As[lrow][lcg], &av, 16);
      __builtin_memcpy(&Bs[lrow][lcg], &bv, 16);
      __syncthreads();
      bfrag a0 = ldfrag(&As[wrow + lr][lq * 8]);
      bfrag a1 = ldfrag(&As[wrow + 16 + lr][lq * 8]);
      bfrag b0 = ldfrag(&Bs[wcol + lr][lq * 8]);
      bfrag b1 = ldfrag(&Bs[wcol + 16 + lr][lq * 8]);
      acc[0][0] = MFMA(a0, b0, acc[0][0]);
      acc[0][1] = MFMA(a0, b1, acc[0][1]);
      acc[1][0] = MFMA(a1, b0, acc[1][0]);
      acc[1][1] = MFMA(a1, b1, acc[1][1]);
    }
  }

#pragma unroll
  for (int i = 0; i < 2; i++)
#pragma unroll
    for (int j = 0; j < 2; j++)
#pragma unroll
      for (int r = 0; r < 4; r++) {
        const int row = rowb + wrow + i * 16 + lq * 4 + r;
        const int col = colb + wcol + j * 16 + lr;
        const size_t o = (size_t)row * N + col;
        Out[o] = X1[o] + 0.5f * acc[i][j][r];
      }
}

// ---------------------------------------------------------------------------
// Flash attention, causal — R9 rewrite.
// Grid (L/64, B*H), 4 waves, 16 q-rows/wave, 64-key tiles.
// Register ping-pong prefetch; conflict-tuned LDS strides:
//   Ks[64][40]  (20 dw/row: 2-way frag reads, free)
//   Vt[64][72]  (36 dw/row ≡ 4: 2-way frag reads; writes <=4-way)
//   Ps[4][16][72]
// Heavy q-tiles dispatched first (reversed blockIdx.x).
// ---------------------------------------------------------------------------
__global__ __launch_bounds__(256) void flash_attn_k(
    const u16* __restrict__ Qc, const u16* __restrict__ Kb,
    const u16* __restrict__ Vb, u16* __restrict__ O) {
  __shared__ __align__(16) u16 Ks[64][40];
  __shared__ __align__(16) u16 Vt[64][72];
  __shared__ __align__(16) u16 Ps[4][16][72];
  const int tid = threadIdx.x, wid = tid >> 6, lane = tid & 63;
  const int lr = lane & 15, lq = lane >> 4;
  const int qt = gridDim.x - 1 - blockIdx.x;    // heavy blocks first
  const int qb = qt * 64;
  const int bh = blockIdx.y;
  const int b = bh / 12, h = bh % 12;
  const int q0 = qb + wid * 16;
  const size_t base = (size_t)b * 2048 * 768 + h * 64;

  bfrag aq[2];
  aq[0] = ldfrag(Qc + base + (size_t)(q0 + lr) * 768 + lq * 8);
  aq[1] = ldfrag(Qc + base + (size_t)(q0 + lr) * 768 + 32 + lq * 8);

  f32x4 o[4] = {};
  float mrow[4] = {NEG_BIG, NEG_BIG, NEG_BIG, NEG_BIG};
  float lrow[4] = {0.0f, 0.0f, 0.0f, 0.0f};

  // staging maps
  const int krow = tid >> 3;            // 0..31 (K rows, +32 second half)
  const int kcol = (tid & 7) * 8;       // 0..56
  const int vkey = tid & 31;            // 0..31 (+32 second half)
  const int vdg = tid >> 5;             // 0..7  (d-group of 8)

  const int nt = qt + 1;

  const u16* kp = Kb + base + (size_t)krow * 768 + kcol;
  const u16* vp = Vb + base + (size_t)vkey * 768 + vdg * 8;

  uint4 kv0, kv1, vv0, vv1;
  __builtin_memcpy(&kv0, kp, 16);
  __builtin_memcpy(&kv1, kp + (size_t)32 * 768, 16);
  __builtin_memcpy(&vv0, vp, 16);
  __builtin_memcpy(&vv1, vp + (size_t)32 * 768, 16);

  for (int kt = 0; kt < nt; kt++) {
    __syncthreads();   // previous tile's LDS reads complete
    __builtin_memcpy(&Ks[krow][kcol], &kv0, 16);
    __builtin_memcpy(&Ks[krow + 32][kcol], &kv1, 16);
    {
      union { uint4 u; u16 s[8]; } a, b2;
      a.u = vv0; b2.u = vv1;
#pragma unroll
      for (int j = 0; j < 8; j++) {
        Vt[vdg * 8 + j][vkey] = a.s[j];
        Vt[vdg * 8 + j][vkey + 32] = b2.s[j];
      }
    }
    __syncthreads();
    if (kt + 1 < nt) {   // prefetch next tile into registers
      const size_t koff = (size_t)(kt + 1) * 64 * 768;
      __builtin_memcpy(&kv0, kp + koff, 16);
      __builtin_memcpy(&kv1, kp + koff + (size_t)32 * 768, 16);
      __builtin_memcpy(&vv0, vp + koff, 16);
      __builtin_memcpy(&vv1, vp + koff + (size_t)32 * 768, 16);
    }

    const int kbk = kt * 64;
    if (kbk <= q0 + 15) {   // wave-uniform causal skip
      f32x4 s4[4] = {};
#pragma unroll
      for (int kg = 0; kg < 2; kg++) {
#pragma unroll
        for (int c = 0; c < 4; c++) {
          bfrag bk = ldfrag(&Ks[c * 16 + lr][kg * 32 + lq * 8]);
          s4[c] = MFMA(aq[kg], bk, s4[c]);
        }
      }
#pragma unroll
      for (int r = 0; r < 4; r++) {
        const int q = q0 + lq * 4 + r;
        float v[4];
        float mx = NEG_BIG;
#pragma unroll
        for (int c = 0; c < 4; c++) {
          v[c] = (kbk + c * 16 + lr > q) ? NEG_BIG : s4[c][r];
          mx = fmaxf(mx, v[c]);
        }
#pragma unroll
        for (int off = 8; off >= 1; off >>= 1)
          mx = fmaxf(mx, __shfl_xor(mx, off, 16));
        const float mn = fmaxf(mrow[r], mx);
        const float alpha = __expf(mrow[r] - mn);
        float sm = 0.0f;
        float p[4];
#pragma unroll
        for (int c = 0; c < 4; c++) {
          p[c] = __expf(v[c] - mn);
          sm += p[c];
        }
#pragma unroll
        for (int off = 8; off >= 1; off >>= 1) sm += __shfl_xor(sm, off, 16);
        lrow[r] = lrow[r] * alpha + sm;
        mrow[r] = mn;
#pragma unroll
        for (int dt = 0; dt < 4; dt++) o[dt][r] *= alpha;
#pragma unroll
        for (int c = 0; c < 4; c++)
          Ps[wid][lq * 4 + r][c * 16 + lr] = f2bf(p[c]);
      }
      __threadfence_block();   // order Ps writes before same-wave re-read
      bfrag pf0 = ldfrag(&Ps[wid][lr][lq * 8]);
      bfrag pf1 = ldfrag(&Ps[wid][lr][32 + lq * 8]);
#pragma unroll
      for (int dt = 0; dt < 4; dt++) {
        bfrag v0 = ldfrag(&Vt[dt * 16 + lr][lq * 8]);
        bfrag v1 = ldfrag(&Vt[dt * 16 + lr][32 + lq * 8]);
        o[dt] = MFMA(pf0, v0, o[dt]);
        o[dt] = MFMA(pf1, v1, o[dt]);
      }
    }
  }

#pragma unroll
  for (int r = 0; r < 4; r++) {
    const float inv = 1.0f / fmaxf(lrow[r], 1e-30f);
    const int q = q0 + lq * 4 + r;
#pragma unroll
    for (int dt = 0; dt < 4; dt++)
      O[base + (size_t)q * 768 + dt * 16 + lr] = f2bf(o[dt][r] * inv);
  }
}

// ---------------------------------------------------------------------------
extern "C" void kernel_launch(void* const* d_in, const int* in_sizes, int n_in,
                              void* d_out, int out_size, void* d_ws,
                              size_t ws_size, hipStream_t stream) {
  (void)in_sizes; (void)n_in; (void)out_size; (void)ws_size;
  const float* x = (const float*)d_in[0];
  const void* mask = d_in[2];

  char* ws = (char*)d_ws;
  u16* Wb  = (u16*)(ws);                        // bf16 arena, 23599104 B
  u16* n1h = (u16*)(ws + 23599104);             // 4096x3072 bf16 (later h1)
  u16* Qb  = (u16*)(ws + 48764928);             // 4096x768 (later n2)
  u16* Kb2 = (u16*)(ws + 55056384);             // 4096x768 (later n2m)
  u16* Vb2 = (u16*)(ws + 61347840);             // 4096x768 (later n2s)
  u16* att = (u16*)(ws + 67639296);             // 4096x768 att, later ht
  u16* hs  = (u16*)(ws + 80222208);             // 4096x1536
  float* mfl = (float*)(ws + 92805120);         // 768 floats
  float* x1 = (float*)d_out;                    // x1 fp32 lives in d_out

  u16* Wq = Wb + 0,        *Wk = Wb + 589824,   *Wv = Wb + 1179648;
  u16* Wo = Wb + 1769472,  *w1 = Wb + 2359296,  *w1t = Wb + 4718592;
  u16* w1s = Wb + 5898240, *w2 = Wb + 7077888,  *w2t = Wb + 9437184;
  u16* w2s = Wb + 10616832;
  u16* n1w = Wb + 11796480, *n1b = Wb + 11797248;
  u16* n2w = Wb + 11798016, *n2b = Wb + 11798784;

  Segs sg;
  const int srcidx[14] = {3, 4, 5, 6, 7, 9, 11, 8, 10, 12, 13, 14, 15, 16};
  const int offs[14] = {0, 589824, 1179648, 1769472, 2359296, 4718592,
                        5898240, 7077888, 9437184, 10616832,
                        11796480, 11797248, 11798016, 11798784};
  const int ns[14] = {589824, 589824, 589824, 589824, 2359296, 1179648,
                      1179648, 2359296, 1179648, 1179648, 768, 768, 768, 768};
  for (int i = 0; i < 14; i++) {
    sg.src[i] = d_in[srcidx[i]];
    sg.off[i] = offs[i];
    sg.n[i] = ns[i];
  }

  mask_conv_k<<<1, 256, 0, stream>>>(mask, mfl);
  convert_k<<<dim3(2304, 14), 256, 0, stream>>>(sg, Wb);

  mink_norm_k<<<4096, 256, 0, stream>>>(x, mfl, n1w, n1b, n1h, nullptr, nullptr);
  gemm_xwt<0><<<dim3(12, 64), 256, 0, stream>>>(n1h, Wq, Qb, nullptr, 4096, 768, 768);
  gemm_xwt<0><<<dim3(12, 64), 256, 0, stream>>>(n1h, Wk, Kb2, nullptr, 4096, 768, 768);
  gemm_xwt<0><<<dim3(12, 64), 256, 0, stream>>>(n1h, Wv, Vb2, nullptr, 4096, 768, 768);
  qcorr_k<<<49152, 64, 0, stream>>>(Qb, mfl);
  flash_attn_k<<<dim3(32, 24), 256, 0, stream>>>(Qb, Kb2, Vb2, att);
  gemm_xwt<1><<<dim3(12, 64), 256, 0, stream>>>(att, Wo, x1, x, 4096, 768, 768);
  mink_norm_k<<<4096, 256, 0, stream>>>(x1, mfl, n2w, n2b, Qb, Kb2, Vb2);
  gemm_xwt<2><<<dim3(48, 64), 256, 0, stream>>>(Qb, w1, n1h, nullptr, 4096, 3072, 768);
  gemm_xwt<3><<<dim3(24, 64), 256, 0, stream>>>(Kb2, w1t, att, nullptr, 4096, 1536, 768);
  gemm_xwt<2><<<dim3(24, 64), 256, 0, stream>>>(Vb2, w1s, hs, nullptr, 4096, 1536, 768);
  ffn2_gemm<<<dim3(12, 64), 256, 0, stream>>>(n1h, att, hs, w2, w2t, w2s,
                                              x1, (float*)d_out);
}

// Round 10
// 512.914 us; speedup vs baseline: 1.1782x; 1.0482x over previous
//
#include <hip/hip_runtime.h>

// LorentzBlock: B=2, L=2048, D=768, H=12, DH=64, DFF=3072
// R10: GEMM ladder step (m93->m97): 128x128 tiles + global_load_lds(16B)
// staging, QKV fused (N=2304), FFN1 fused (N=6144, mask folded into weights
// at convert time: (x*m)@W^T == x@(W*m)^T exactly since m in {0,1}).
// flash_attn unchanged from R9.

typedef unsigned short u16;
typedef __bf16 bfrag __attribute__((ext_vector_type(8)));
typedef float f32x4 __attribute__((ext_vector_type(4)));

#define MFMA(a, b, c) __builtin_amdgcn_mfma_f32_16x16x32_bf16(a, b, c, 0, 0, 0)
#define NEG_BIG (-30000.0f)
#define ASYNC16(g, l)                                                        \
  __builtin_amdgcn_global_load_lds(                                          \
      (const __attribute__((address_space(1))) unsigned int*)(g),            \
      (__attribute__((address_space(3))) unsigned int*)(l), 16, 0, 0)

__device__ __forceinline__ float bf2f(u16 u) {
  unsigned int v = ((unsigned int)u) << 16;
  float f; __builtin_memcpy(&f, &v, 4); return f;
}
__device__ __forceinline__ u16 f2bf(float f) {
  unsigned int v; __builtin_memcpy(&v, &f, 4);
  v += 0x7fffu + ((v >> 16) & 1u);   // RNE
  return (u16)(v >> 16);
}
__device__ __forceinline__ bfrag ldfrag(const u16* p) {
  bfrag v; __builtin_memcpy(&v, p, 16); return v;
}

// ---------------------------------------------------------------------------
// Mask canonicalization -> float[768].
// ---------------------------------------------------------------------------
__global__ __launch_bounds__(256) void mask_conv_k(const void* __restrict__ mask,
                                                   float* __restrict__ mfl) {
  __shared__ int msh;
  if (threadIdx.x == 0) msh = 0;
  __syncthreads();
  const unsigned int* w = (const unsigned int*)mask;
  if (threadIdx.x < 192) {
    const unsigned int v = w[threadIdx.x];
    if ((v & 0xFFFFu) == 0x3F80u) atomicOr(&msh, 4);
    else if (v == 0x3F800000u) atomicOr(&msh, 2);
    else if (v >= 2u) atomicOr(&msh, 1);
  }
  __syncthreads();
  const int m = msh;
  const int mode = (m & 4) ? 3 : (m & 2) ? 2 : (m & 1) ? 1 : 0;
  for (int i = threadIdx.x; i < 768; i += 256) {
    int b;
    if (mode == 3) b = ((const u16*)mask)[i] != 0;
    else if (mode == 2) b = ((const float*)mask)[i] != 0.0f;
    else if (mode == 1) b = ((const unsigned char*)mask)[i] != 0;
    else b = ((const int*)mask)[i] != 0;
    mfl[i] = (float)b;
  }
}

// ---------------------------------------------------------------------------
// Convert fp32 weight segments -> bf16 arena. mmode: 0 none, 1 *m[k],
// 2 *(1-m[k]) with k = i % 768 (mask fold for w1_t / w1_s).
// ---------------------------------------------------------------------------
struct Segs {
  const void* src[14];
  int off[14];
  int n[14];
  int mmode[14];
};

__global__ __launch_bounds__(256) void convert_k(Segs segs, u16* __restrict__ dstb,
                                                 const float* __restrict__ mfl) {
  const int seg = blockIdx.y;
  const int n = segs.n[seg];
  const int mm = segs.mmode[seg];
  u16* dst = dstb + segs.off[seg];
  const float* src = (const float*)segs.src[seg];
  for (int i = (blockIdx.x * 256 + threadIdx.x) * 4; i < n; i += gridDim.x * 1024) {
    float4 v;
    __builtin_memcpy(&v, src + i, 16);
    if (mm) {
      const int k = i % 768;
      float m0 = mfl[k], m1 = mfl[k + 1], m2 = mfl[k + 2], m3 = mfl[k + 3];
      if (mm == 2) { m0 = 1.f - m0; m1 = 1.f - m1; m2 = 1.f - m2; m3 = 1.f - m3; }
      v.x *= m0; v.y *= m1; v.z *= m2; v.w *= m3;
    }
    dst[i] = f2bf(v.x); dst[i + 1] = f2bf(v.y);
    dst[i + 2] = f2bf(v.z); dst[i + 3] = f2bf(v.w);
  }
}

// ---------------------------------------------------------------------------
// Minkowski LayerNorm. fp32 input, bf16 output(s).
// ---------------------------------------------------------------------------
__global__ __launch_bounds__(256) void mink_norm_k(
    const float* __restrict__ X, const float* __restrict__ mf,
    const u16* __restrict__ w, const u16* __restrict__ bias,
    u16* __restrict__ Y) {
  __shared__ float red[8];
  const int row = blockIdx.x, tid = threadIdx.x;
  const int wid = tid >> 6, lane = tid & 63;
  const size_t roff = (size_t)row * 768;

  float xv[3], mv[3];
  int idx[3];
#pragma unroll
  for (int i = 0; i < 3; i++) {
    idx[i] = tid + i * 256;
    xv[i] = X[roff + idx[i]];
    mv[i] = mf[idx[i]];
  }
  float s = xv[0] + xv[1] + xv[2];
#pragma unroll
  for (int o = 32; o >= 1; o >>= 1) s += __shfl_xor(s, o, 64);
  if (lane == 0) red[wid] = s;
  __syncthreads();
  const float mean = (red[0] + red[1] + red[2] + red[3]) * (1.0f / 768.0f);
  __syncthreads();

  float xc[3], ss = 0.0f, sm = 0.0f;
#pragma unroll
  for (int i = 0; i < 3; i++) {
    xc[i] = xv[i] - mean;
    ss += xc[i] * xc[i];
    sm += xc[i] * xc[i] * mv[i];
  }
#pragma unroll
  for (int o = 32; o >= 1; o >>= 1) {
    ss += __shfl_xor(ss, o, 64);
    sm += __shfl_xor(sm, o, 64);
  }
  if (lane == 0) { red[wid] = ss; red[4 + wid] = sm; }
  __syncthreads();
  const float sumsq = red[0] + red[1] + red[2] + red[3];
  const float summ = red[4] + red[5] + red[6] + red[7];
  const float var = sumsq * (1.0f / 768.0f);
  const float eta = sumsq - 2.0f * summ;
  const float rs = 1.0f / sqrtf(var + 1e-5f);
  const float re = 1.0f / sqrtf(fabsf(eta) + 1e-5f);

#pragma unroll
  for (int i = 0; i < 3; i++) {
    const float xn = xc[i] * 0.5f * (rs + re);
    Y[roff + idx[i]] = f2bf(bf2f(w[idx[i]]) * xn + bf2f(bias[idx[i]]));
  }
}

// ---------------------------------------------------------------------------
// Q Lorentz correction, in place. 4 rows per block (one per wave).
// ---------------------------------------------------------------------------
__global__ __launch_bounds__(256) void qcorr_k(u16* __restrict__ Q,
                                               const float* __restrict__ mf) {
  const int idx = blockIdx.x * 4 + (threadIdx.x >> 6);  // (b*2048+l)*12+h
  const int t = threadIdx.x & 63;
  const int h = idx % 12;
  const int bl = idx / 12;
  const size_t off = (size_t)bl * 768 + h * 64 + t;
  const float q = bf2f(Q[off]);
  const float m = mf[h * 64 + t];
  float q2 = q * q, qm2 = q * q * m;
#pragma unroll
  for (int o = 32; o >= 1; o >>= 1) {
    q2 += __shfl_xor(q2, o, 64);
    qm2 += __shfl_xor(qm2, o, 64);
  }
  const float qn = sqrtf(q2), qtn = sqrtf(qm2);
  const float sf = (qtn > 1e-6f) ? qn / fmaxf(qtn, 1e-8f) : 0.0f;
  Q[off] = f2bf(q * (1.0f - 0.5f * sf * m) * 0.125f);
}

// ---------------------------------------------------------------------------
// 128x128 MFMA GEMM core (m97 structure). As/Bs unpadded [128][32],
// global_load_lds 16B staging, 16 MFMA + 8 ds_read_b128 per wave per K-iter.
// Wave grid 2x2, each wave 64x64 (4x4 tiles). acc[4][4] per lane.
// ---------------------------------------------------------------------------
__device__ __forceinline__ void gemm128_loop(
    const u16* __restrict__ Ab, const u16* __restrict__ Wb2,
    int K, int lda, u16 (*As)[32], u16 (*Bs)[32], f32x4 acc[4][4]) {
  const int tid = threadIdx.x;
  const int wid = tid >> 6, lane = tid & 63;
  const int lr = lane & 15, lq = lane >> 4;
  const int srow = wid * 32 + (lane >> 2);
  const int scol = (lane & 3) * 8;
  const u16* ga0 = Ab + (size_t)srow * lda + scol;
  const u16* ga1 = Ab + (size_t)(srow + 16) * lda + scol;
  const u16* gb0 = Wb2 + (size_t)srow * K + scol;
  const u16* gb1 = Wb2 + (size_t)(srow + 16) * K + scol;
  u16* la0 = &As[wid * 32][0];
  u16* la1 = &As[wid * 32 + 16][0];
  u16* lb0 = &Bs[wid * 32][0];
  u16* lb1 = &Bs[wid * 32 + 16][0];
  const int wr = (wid >> 1) * 64, wc = (wid & 1) * 64;

  for (int k0 = 0; k0 < K; k0 += 32) {
    __syncthreads();            // prior iter's LDS reads complete
    ASYNC16(ga0 + k0, la0);
    ASYNC16(ga1 + k0, la1);
    ASYNC16(gb0 + k0, lb0);
    ASYNC16(gb1 + k0, lb1);
    __syncthreads();            // compiler drains vmcnt before barrier
    bfrag af[4], bf4[4];
#pragma unroll
    for (int i = 0; i < 4; i++) af[i] = ldfrag(&As[wr + i * 16 + lr][lq * 8]);
#pragma unroll
    for (int j = 0; j < 4; j++) bf4[j] = ldfrag(&Bs[wc + j * 16 + lr][lq * 8]);
#pragma unroll
    for (int i = 0; i < 4; i++)
#pragma unroll
      for (int j = 0; j < 4; j++)
        acc[i][j] = MFMA(af[i], bf4[j], acc[i][j]);
  }
}

// ---------------------------------------------------------------------------
// Fused multi-segment GEMM, bf16 out: C_seg = epi(A @ Wseg^T).
// Segments partition blockIdx.x. epi: 0 none, 2 gelu(exact), 3 silu.
// ---------------------------------------------------------------------------
struct GSeg { const u16* W; u16* C; int ldc; int nblk; int epi; };
struct GArgs { GSeg s[3]; };

__global__ __launch_bounds__(256) void gemm128_fused(
    const u16* __restrict__ A, int lda, int K, GArgs args) {
  __shared__ __align__(16) u16 As[128][32];
  __shared__ __align__(16) u16 Bs[128][32];
  int cb = blockIdx.x, seg = 0;
  while (cb >= args.s[seg].nblk) { cb -= args.s[seg].nblk; seg++; }
  const GSeg g = args.s[seg];
  const int rowb = blockIdx.y * 128, colb = cb * 128;
  f32x4 acc[4][4] = {};
  gemm128_loop(A + (size_t)rowb * lda, g.W + (size_t)colb * K, K, lda,
               As, Bs, acc);

  const int lane = threadIdx.x & 63, wid = threadIdx.x >> 6;
  const int lr = lane & 15, lq = lane >> 4;
  const int wr = (wid >> 1) * 64, wc = (wid & 1) * 64;
#pragma unroll
  for (int i = 0; i < 4; i++)
#pragma unroll
    for (int j = 0; j < 4; j++)
#pragma unroll
      for (int r = 0; r < 4; r++) {
        const int row = rowb + wr + i * 16 + lq * 4 + r;
        const int col = colb + wc + j * 16 + lr;
        float v = acc[i][j][r];
        if (g.epi == 2) v = 0.5f * v * (1.0f + erff(v * 0.70710678118654752f));
        else if (g.epi == 3) v = v / (1.0f + __expf(-v));
        g.C[(size_t)row * g.ldc + col] = f2bf(v);
      }
}

// ---------------------------------------------------------------------------
// Single GEMM with fp32 residual out: Out = A @ W^T + R. (Wo projection.)
// ---------------------------------------------------------------------------
__global__ __launch_bounds__(256) void gemm128_res(
    const u16* __restrict__ A, const u16* __restrict__ W,
    const float* __restrict__ R, float* __restrict__ Out, int lda, int K,
    int N) {
  __shared__ __align__(16) u16 As[128][32];
  __shared__ __align__(16) u16 Bs[128][32];
  const int rowb = blockIdx.y * 128, colb = blockIdx.x * 128;
  f32x4 acc[4][4] = {};
  gemm128_loop(A + (size_t)rowb * lda, W + (size_t)colb * K, K, lda,
               As, Bs, acc);

  const int lane = threadIdx.x & 63, wid = threadIdx.x >> 6;
  const int lr = lane & 15, lq = lane >> 4;
  const int wr = (wid >> 1) * 64, wc = (wid & 1) * 64;
#pragma unroll
  for (int i = 0; i < 4; i++)
#pragma unroll
    for (int j = 0; j < 4; j++)
#pragma unroll
      for (int r = 0; r < 4; r++) {
        const int row = rowb + wr + i * 16 + lq * 4 + r;
        const int col = colb + wc + j * 16 + lr;
        const size_t o = (size_t)row * N + col;
        Out[o] = acc[i][j][r] + R[o];
      }
}

// ---------------------------------------------------------------------------
// FFN2: Out = X1 + 0.5*(h1@w2^T + ht@w2_t^T + hs@w2_s^T). fp32 out, X1
// aliases Out (same-element read-before-write).
// ---------------------------------------------------------------------------
__global__ __launch_bounds__(256) void ffn2_128(
    const u16* __restrict__ H1, const u16* __restrict__ Ht,
    const u16* __restrict__ Hs, const u16* __restrict__ W2,
    const u16* __restrict__ W2t, const u16* __restrict__ W2s,
    const float* X1, float* Out) {
  __shared__ __align__(16) u16 As[128][32];
  __shared__ __align__(16) u16 Bs[128][32];
  const int rowb = blockIdx.y * 128, colb = blockIdx.x * 128;
  f32x4 acc[4][4] = {};
  gemm128_loop(H1 + (size_t)rowb * 3072, W2 + (size_t)colb * 3072, 3072, 3072,
               As, Bs, acc);
  gemm128_loop(Ht + (size_t)rowb * 1536, W2t + (size_t)colb * 1536, 1536, 1536,
               As, Bs, acc);
  gemm128_loop(Hs + (size_t)rowb * 1536, W2s + (size_t)colb * 1536, 1536, 1536,
               As, Bs, acc);

  const int lane = threadIdx.x & 63, wid = threadIdx.x >> 6;
  const int lr = lane & 15, lq = lane >> 4;
  const int wr = (wid >> 1) * 64, wc = (wid & 1) * 64;
#pragma unroll
  for (int i = 0; i < 4; i++)
#pragma unroll
    for (int j = 0; j < 4; j++)
#pragma unroll
      for (int r = 0; r < 4; r++) {
        const int row = rowb + wr + i * 16 + lq * 4 + r;
        const int col = colb + wc + j * 16 + lr;
        const size_t o = (size_t)row * 768 + col;
        Out[o] = X1[o] + 0.5f * acc[i][j][r];
      }
}

// ---------------------------------------------------------------------------
// Flash attention, causal (R9 version, unchanged).
// ---------------------------------------------------------------------------
__global__ __launch_bounds__(256) void flash_attn_k(
    const u16* __restrict__ Qc, const u16* __restrict__ Kb,
    const u16* __restrict__ Vb, u16* __restrict__ O) {
  __shared__ __align__(16) u16 Ks[64][40];
  __shared__ __align__(16) u16 Vt[64][72];
  __shared__ __align__(16) u16 Ps[4][16][72];
  const int tid = threadIdx.x, wid = tid >> 6, lane = tid & 63;
  const int lr = lane & 15, lq = lane >> 4;
  const int qt = gridDim.x - 1 - blockIdx.x;
  const int qb = qt * 64;
  const int bh = blockIdx.y;
  const int b = bh / 12, h = bh % 12;
  const int q0 = qb + wid * 16;
  const size_t base = (size_t)b * 2048 * 768 + h * 64;

  bfrag aq[2];
  aq[0] = ldfrag(Qc + base + (size_t)(q0 + lr) * 768 + lq * 8);
  aq[1] = ldfrag(Qc + base + (size_t)(q0 + lr) * 768 + 32 + lq * 8);

  f32x4 o[4] = {};
  float mrow[4] = {NEG_BIG, NEG_BIG, NEG_BIG, NEG_BIG};
  float lrow[4] = {0.0f, 0.0f, 0.0f, 0.0f};

  const int krow = tid >> 3;
  const int kcol = (tid & 7) * 8;
  const int vkey = tid & 31;
  const int vdg = tid >> 5;

  const int nt = qt + 1;

  const u16* kp = Kb + base + (size_t)krow * 768 + kcol;
  const u16* vp = Vb + base + (size_t)vkey * 768 + vdg * 8;

  uint4 kv0, kv1, vv0, vv1;
  __builtin_memcpy(&kv0, kp, 16);
  __builtin_memcpy(&kv1, kp + (size_t)32 * 768, 16);
  __builtin_memcpy(&vv0, vp, 16);
  __builtin_memcpy(&vv1, vp + (size_t)32 * 768, 16);

  for (int kt = 0; kt < nt; kt++) {
    __syncthreads();
    __builtin_memcpy(&Ks[krow][kcol], &kv0, 16);
    __builtin_memcpy(&Ks[krow + 32][kcol], &kv1, 16);
    {
      union { uint4 u; u16 s[8]; } a, b2;
      a.u = vv0; b2.u = vv1;
#pragma unroll
      for (int j = 0; j < 8; j++) {
        Vt[vdg * 8 + j][vkey] = a.s[j];
        Vt[vdg * 8 + j][vkey + 32] = b2.s[j];
      }
    }
    __syncthreads();
    if (kt + 1 < nt) {
      const size_t koff = (size_t)(kt + 1) * 64 * 768;
      __builtin_memcpy(&kv0, kp + koff, 16);
      __builtin_memcpy(&kv1, kp + koff + (size_t)32 * 768, 16);
      __builtin_memcpy(&vv0, vp + koff, 16);
      __builtin_memcpy(&vv1, vp + koff + (size_t)32 * 768, 16);
    }

    const int kbk = kt * 64;
    if (kbk <= q0 + 15) {
      f32x4 s4[4] = {};
#pragma unroll
      for (int kg = 0; kg < 2; kg++) {
#pragma unroll
        for (int c = 0; c < 4; c++) {
          bfrag bk = ldfrag(&Ks[c * 16 + lr][kg * 32 + lq * 8]);
          s4[c] = MFMA(aq[kg], bk, s4[c]);
        }
      }
#pragma unroll
      for (int r = 0; r < 4; r++) {
        const int q = q0 + lq * 4 + r;
        float v[4];
        float mx = NEG_BIG;
#pragma unroll
        for (int c = 0; c < 4; c++) {
          v[c] = (kbk + c * 16 + lr > q) ? NEG_BIG : s4[c][r];
          mx = fmaxf(mx, v[c]);
        }
#pragma unroll
        for (int off = 8; off >= 1; off >>= 1)
          mx = fmaxf(mx, __shfl_xor(mx, off, 16));
        const float mn = fmaxf(mrow[r], mx);
        const float alpha = __expf(mrow[r] - mn);
        float sm = 0.0f;
        float p[4];
#pragma unroll
        for (int c = 0; c < 4; c++) {
          p[c] = __expf(v[c] - mn);
          sm += p[c];
        }
#pragma unroll
        for (int off = 8; off >= 1; off >>= 1) sm += __shfl_xor(sm, off, 16);
        lrow[r] = lrow[r] * alpha + sm;
        mrow[r] = mn;
#pragma unroll
        for (int dt = 0; dt < 4; dt++) o[dt][r] *= alpha;
#pragma unroll
        for (int c = 0; c < 4; c++)
          Ps[wid][lq * 4 + r][c * 16 + lr] = f2bf(p[c]);
      }
      __threadfence_block();
      bfrag pf0 = ldfrag(&Ps[wid][lr][lq * 8]);
      bfrag pf1 = ldfrag(&Ps[wid][lr][32 + lq * 8]);
#pragma unroll
      for (int dt = 0; dt < 4; dt++) {
        bfrag v0 = ldfrag(&Vt[dt * 16 + lr][lq * 8]);
        bfrag v1 = ldfrag(&Vt[dt * 16 + lr][32 + lq * 8]);
        o[dt] = MFMA(pf0, v0, o[dt]);
        o[dt] = MFMA(pf1, v1, o[dt]);
      }
    }
  }

#pragma unroll
  for (int r = 0; r < 4; r++) {
    const float inv = 1.0f / fmaxf(lrow[r], 1e-30f);
    const int q = q0 + lq * 4 + r;
#pragma unroll
    for (int dt = 0; dt < 4; dt++)
      O[base + (size_t)q * 768 + dt * 16 + lr] = f2bf(o[dt][r] * inv);
  }
}

// ---------------------------------------------------------------------------
extern "C" void kernel_launch(void* const* d_in, const int* in_sizes, int n_in,
                              void* d_out, int out_size, void* d_ws,
                              size_t ws_size, hipStream_t stream) {
  (void)in_sizes; (void)n_in; (void)out_size; (void)ws_size;
  const float* x = (const float*)d_in[0];
  const void* mask = d_in[2];

  char* ws = (char*)d_ws;
  u16* Wb  = (u16*)(ws);                        // bf16 arena, 23599104 B
  u16* n1h = (u16*)(ws + 23599104);             // 4096x3072 bf16 (later h1)
  u16* Qb  = (u16*)(ws + 48764928);             // 4096x768 (later n2)
  u16* Kb2 = (u16*)(ws + 55056384);             // 4096x768
  u16* Vb2 = (u16*)(ws + 61347840);             // 4096x768
  u16* att = (u16*)(ws + 67639296);             // 4096x768 att, later ht (x1536)
  u16* hs  = (u16*)(ws + 80222208);             // 4096x1536
  float* mfl = (float*)(ws + 92805120);         // 768 floats
  float* x1 = (float*)d_out;                    // x1 fp32 lives in d_out

  u16* Wq = Wb + 0,        *Wk = Wb + 589824,   *Wv = Wb + 1179648;
  u16* Wo = Wb + 1769472,  *w1 = Wb + 2359296,  *w1t = Wb + 4718592;
  u16* w1s = Wb + 5898240, *w2 = Wb + 7077888,  *w2t = Wb + 9437184;
  u16* w2s = Wb + 10616832;
  u16* n1w = Wb + 11796480, *n1b = Wb + 11797248;
  u16* n2w = Wb + 11798016, *n2b = Wb + 11798784;

  Segs sg;
  const int srcidx[14] = {3, 4, 5, 6, 7, 9, 11, 8, 10, 12, 13, 14, 15, 16};
  const int offs[14] = {0, 589824, 1179648, 1769472, 2359296, 4718592,
                        5898240, 7077888, 9437184, 10616832,
                        11796480, 11797248, 11798016, 11798784};
  const int ns[14] = {589824, 589824, 589824, 589824, 2359296, 1179648,
                      1179648, 2359296, 1179648, 1179648, 768, 768, 768, 768};
  const int mms[14] = {0, 0, 0, 0, 0, 1, 2, 0, 0, 0, 0, 0, 0, 0};
  for (int i = 0; i < 14; i++) {
    sg.src[i] = d_in[srcidx[i]];
    sg.off[i] = offs[i];
    sg.n[i] = ns[i];
    sg.mmode[i] = mms[i];
  }

  mask_conv_k<<<1, 256, 0, stream>>>(mask, mfl);
  convert_k<<<dim3(2304, 14), 256, 0, stream>>>(sg, Wb, mfl);

  // n1 = mink_norm(x)
  mink_norm_k<<<4096, 256, 0, stream>>>(x, mfl, n1w, n1b, n1h);

  // Q,K,V fused (N=2304)
  GArgs qkv;
  qkv.s[0] = {Wq, Qb, 768, 6, 0};
  qkv.s[1] = {Wk, Kb2, 768, 6, 0};
  qkv.s[2] = {Wv, Vb2, 768, 6, 0};
  gemm128_fused<<<dim3(18, 32), 256, 0, stream>>>(n1h, 768, 768, qkv);

  qcorr_k<<<12288, 256, 0, stream>>>(Qb, mfl);
  flash_attn_k<<<dim3(32, 24), 256, 0, stream>>>(Qb, Kb2, Vb2, att);

  // x1 = x + att @ Wo^T  (fp32, into d_out)
  gemm128_res<<<dim3(6, 32), 256, 0, stream>>>(att, Wo, x, x1, 768, 768, 768);

  // n2 = mink_norm(x1) -> Qb (single output; mask folded into FFN1 weights)
  mink_norm_k<<<4096, 256, 0, stream>>>(x1, mfl, n2w, n2b, Qb);

  // FFN1 fused (N=6144): h1 = gelu(n2@w1^T), ht = silu(n2@w1t_m^T),
  // hs = gelu(n2@w1s_m^T)
  GArgs ffn1;
  ffn1.s[0] = {w1, n1h, 3072, 24, 2};
  ffn1.s[1] = {w1t, att, 1536, 12, 3};
  ffn1.s[2] = {w1s, hs, 1536, 12, 2};
  gemm128_fused<<<dim3(48, 32), 256, 0, stream>>>(Qb, 768, 768, ffn1);

  // out = x1 + 0.5*(h1@w2^T + ht@w2_t^T + hs@w2_s^T)
  ffn2_128<<<dim3(6, 32), 256, 0, stream>>>(n1h, att, hs, w2, w2t, w2s,
                                            x1, (float*)d_out);
}